// Round 8
// baseline (577.112 us; speedup 1.0000x reference)
//
#include <hip/hip_runtime.h>
#include <stdint.h>

#define B_ 8
#define L_ 2500
#define D_ 512
#define Y_ 8921
#define LP 2560   // padded L = 20*128
#define YP 8960   // padded Y = 70*128 = 280*32
#define BLK 128
#define NKT 16    // K-chunks of 32 (D/32)
#define NS 4      // l-splits
#define LTS 5     // l-tiles of 128 per split
#define YT32 280  // YP/32

typedef float  f32x16 __attribute__((ext_vector_type(16)));
typedef __bf16 bf16x8 __attribute__((ext_vector_type(8)));
typedef unsigned short u16;
typedef unsigned int u32;

// ---- f32 -> bf16 (RTNE) pack helpers ----
__device__ __forceinline__ u32 pack2(float a, float b) {
  u32 ua = __float_as_uint(a); ua = (ua + 0x7FFFu + ((ua >> 16) & 1u)) >> 16;
  u32 ub = __float_as_uint(b); ub = (ub + 0x7FFFu + ((ub >> 16) & 1u)) >> 16;
  return ua | (ub << 16);
}

// x [B,L,D] f32 -> [B,LP,D] bf16 row-major (pad rows zero)
__global__ void cvt_x_kernel(const float* __restrict__ x, u16* __restrict__ xb) {
  int idx = blockIdx.x * 256 + threadIdx.x;   // one 8-elem chunk
  int row = idx >> 6;                         // b*LP + l
  int c8  = (idx & 63) << 3;
  int b = row / LP;
  int l = row - b * LP;
  uint4 o;
  if (l < L_) {
    const float* s = x + (size_t)(b * L_ + l) * D_ + c8;
    float4 f0 = *(const float4*)s;
    float4 f1 = *(const float4*)(s + 4);
    o.x = pack2(f0.x, f0.y); o.y = pack2(f0.z, f0.w);
    o.z = pack2(f1.x, f1.y); o.w = pack2(f1.z, f1.w);
  } else {
    o = make_uint4(0u, 0u, 0u, 0u);
  }
  *(uint4*)(xb + (size_t)row * D_ + c8) = o;
}

// U,Wf [Y,D] f32 -> MFMA-A-fragment-packed bf16:
//   chunk i = (yt32*32 + ks)*64 + lane holds A[y = yt32*32 + (lane&31)]
//                                         [k = ks*16 + (lane>>5)*8 .. +8)
__global__ void cvt_wpk_kernel(const float* __restrict__ U, const float* __restrict__ Wf,
                               u16* __restrict__ Upk, u16* __restrict__ Wpk) {
  int gid = blockIdx.x * 256 + threadIdx.x;   // 2 * 280*32*64 chunks
  const int half = YT32 * 32 * 64;
  const float* src = U; u16* dst = Upk;
  int i = gid;
  if (gid >= half) { i -= half; src = Wf; dst = Wpk; }
  const int lane = i & 63;
  const int ks   = (i >> 6) & 31;
  const int yt   = i >> 11;
  const int y    = yt * 32 + (lane & 31);
  const int k    = ks * 16 + (lane >> 5) * 8;
  uint4 o;
  if (y < Y_) {
    const float* sp = src + (size_t)y * D_ + k;
    float4 f0 = *(const float4*)sp;
    float4 f1 = *(const float4*)(sp + 4);
    o.x = pack2(f0.x, f0.y); o.y = pack2(f0.z, f0.w);
    o.z = pack2(f1.x, f1.y); o.w = pack2(f1.z, f1.w);
  } else {
    o = make_uint4(0u, 0u, 0u, 0u);
  }
  *(uint4*)(dst + (size_t)i * 8) = o;
}

__device__ __forceinline__ void async16(const u16* g, u16* l) {
  __builtin_amdgcn_global_load_lds(
      (const __attribute__((address_space(1))) u32*)g,
      (__attribute__((address_space(3))) u32*)l, 16, 0, 0);
}

// Fused per (y-tile 128, b, l-split). 4 waves; wave wv owns y rows [wv*32,+32)
// via ONE 32x32 A-tile. A-frags (U,W) stream direct from global (packed layout,
// lane-coalesced). Only X goes through LDS (8 KB, XOR-4 chunk swizzle).
// 32x32x16 bf16 MFMA; no max-tracking (|att| < ~2): plain sum-exp.
// Partial layout: part[((b*70 + yt)*NS + s)*256 + {0,128} + ylocal]  (Z, W)
__global__ __launch_bounds__(256, 2) void fused_kernel(
    const u16* __restrict__ xb,    // [B][LP][512] bf16 row-major
    const u16* __restrict__ Upk,   // packed A-frags
    const u16* __restrict__ Wpk,   // packed A-frags
    float* __restrict__ part)
{
  __shared__ __align__(16) u16 sX[128 * 32];   // [row 128][32 bf16 = 4 chunks of 16B]

  const int t    = threadIdx.x;
  const int lane = t & 63;
  const int wv   = t >> 6;
  const int c32  = lane & 31;     // column within 32 (l for B / C/D)
  const int h    = lane >> 5;     // lane half (selects k-subchunk / C/D row +4h)
  const int b    = blockIdx.y;
  const int s    = blockIdx.z;
  const int yt32 = blockIdx.x * 4 + wv;

  // A-frag global bases (bf16-elem units). aX(ks) at +ks*512; kt covers ks=2kt,2kt+1.
  const u16* pU = Upk + (size_t)yt32 * 16384 + lane * 8;
  const u16* pW = Wpk + (size_t)yt32 * 16384 + lane * 8;

  // X staging: thread t -> LDS rows (t>>2) and (t>>2)+64, chunk slot t&3.
  // Global chunk XOR-4-swizzled by row so frag reads spread banks.
  const int srow = t >> 2;
  const int gch  = (t & 3) ^ (srow & 3);
  const u16* gXb = xb + ((size_t)b * LP + srow) * 512 + gch * 8;

  // per-lane partial sums over this lane's l-columns, for its 16 C/D y-rows
  float Zr[16], Wr[16];
#pragma unroll
  for (int i = 0; i < 16; ++i) { Zr[i] = 0.f; Wr[i] = 0.f; }

  for (int ltl = 0; ltl < LTS; ++ltl) {
    const int l0 = (s * LTS + ltl) * BLK;
    const u16* gX = gXb + (size_t)l0 * 512;

    f32x16 accA[4], accS[4];
#pragma unroll
    for (int cl = 0; cl < 4; ++cl) {
      accA[cl] = (f32x16)(0.f);
      accS[cl] = (f32x16)(0.f);
    }

    for (int kt = 0; kt < NKT; ++kt) {
      __syncthreads();                      // previous tile consumed
      async16(gX + kt * 32,             sX + t * 8);
      async16(gX + kt * 32 + 64 * 512,  sX + 2048 + t * 8);
      __syncthreads();                      // staging visible

      const bf16x8 aU0 = *(const bf16x8*)(const void*)(pU + kt * 1024);
      const bf16x8 aU1 = *(const bf16x8*)(const void*)(pU + kt * 1024 + 512);
      const bf16x8 aW0 = *(const bf16x8*)(const void*)(pW + kt * 1024);
      const bf16x8 aW1 = *(const bf16x8*)(const void*)(pW + kt * 1024 + 512);
#pragma unroll
      for (int cl = 0; cl < 4; ++cl) {
        const int r  = cl * 32 + c32;                 // B row (l-col)
        const int sw = r & 3;
        const bf16x8 b0 = *(const bf16x8*)(const void*)(sX + r * 32 + ((h     ^ sw) << 3));
        const bf16x8 b1 = *(const bf16x8*)(const void*)(sX + r * 32 + (((2+h) ^ sw) << 3));
        accA[cl] = __builtin_amdgcn_mfma_f32_32x32x16_bf16(aU0, b0, accA[cl], 0, 0, 0);
        accA[cl] = __builtin_amdgcn_mfma_f32_32x32x16_bf16(aU1, b1, accA[cl], 0, 0, 0);
        accS[cl] = __builtin_amdgcn_mfma_f32_32x32x16_bf16(aW0, b0, accS[cl], 0, 0, 0);
        accS[cl] = __builtin_amdgcn_mfma_f32_32x32x16_bf16(aW1, b1, accS[cl], 0, 0, 0);
      }
    }

    // per-lane accumulate exp / exp*s. C/D: col=lane&31, row=(reg&3)+8*(reg>>2)+4h
    const bool boundary = (l0 + BLK > L_);   // wave-uniform; 1 of 20 tiles
#pragma unroll
    for (int cl = 0; cl < 4; ++cl) {
      const bool dead = boundary && (l0 + cl * 32 + c32 >= L_);
#pragma unroll
      for (int reg = 0; reg < 16; ++reg) {
        float v = accA[cl][reg];
        if (dead) v = -1e30f;                // exp -> 0
        const float p = __expf(v);
        Zr[reg] += p;
        Wr[reg] = fmaf(p, accS[cl][reg], Wr[reg]);
      }
    }
  }

  // butterfly sum over the 32 l-columns
#pragma unroll
  for (int reg = 0; reg < 16; ++reg) {
    float Z0 = Zr[reg], W0 = Wr[reg];
#pragma unroll
    for (int st = 1; st <= 16; st <<= 1) {
      Z0 += __shfl_xor(Z0, st);
      W0 += __shfl_xor(W0, st);
    }
    Zr[reg] = Z0; Wr[reg] = W0;
  }

  // write partial (Z,W); lanes c32==0 (h=0,1) hold the two disjoint row-sets
  if (c32 == 0) {
    float* p = part + ((size_t)(b * 70 + blockIdx.x) * NS + s) * 256;
#pragma unroll
    for (int reg = 0; reg < 16; ++reg) {
      const int yl = wv * 32 + (reg & 3) + 8 * (reg >> 2) + 4 * h;
      p[yl]       = Zr[reg];
      p[128 + yl] = Wr[reg];
    }
  }
}

// Merge NS partials per (b,y); y = W/Z + bias; BCE partial -> atomicAdd.
__global__ void combine_kernel(const float* __restrict__ part,
                               const float* __restrict__ bias,
                               const float* __restrict__ target,
                               float* __restrict__ out) {
  const int idx = blockIdx.x * 256 + threadIdx.x;
  float lpart = 0.f;
  if (idx < B_ * Y_) {
    const int b = idx / Y_;
    const int y = idx - b * Y_;
    const int yt = y >> 7, yl = y & 127;
    const float* p = part + ((size_t)(b * 70 + yt) * NS) * 256 + yl;
    float Z = 0.f, W = 0.f;
#pragma unroll
    for (int s2 = 0; s2 < NS; ++s2) {
      Z += p[s2 * 256];
      W += p[s2 * 256 + 128];
    }
    const float yv = W / Z + bias[y];
    out[idx] = yv;
    const float tg = target[idx];
    lpart = fmaxf(yv, 0.f) - yv * tg + log1pf(__expf(-fabsf(yv)));
  }
  lpart += __shfl_xor(lpart, 1);  lpart += __shfl_xor(lpart, 2);
  lpart += __shfl_xor(lpart, 4);  lpart += __shfl_xor(lpart, 8);
  lpart += __shfl_xor(lpart, 16); lpart += __shfl_xor(lpart, 32);
  if ((threadIdx.x & 63) == 0)
    atomicAdd(out + (size_t)B_ * Y_, lpart * (1.0f / (B_ * Y_)));
}

extern "C" void kernel_launch(void* const* d_in, const int* in_sizes, int n_in,
                              void* d_out, int out_size, void* d_ws, size_t ws_size,
                              hipStream_t stream) {
  const float* x      = (const float*)d_in[0];
  const float* target = (const float*)d_in[1];
  // d_in[2] = text_inputs (unused by reference)
  const float* U      = (const float*)d_in[3];
  const float* Wf     = (const float*)d_in[4];
  const float* bias   = (const float*)d_in[5];
  float* out = (float*)d_out;

  u16* xb  = (u16*)d_ws;                       // [B][LP][512]      20.97 MB
  u16* Upk = xb + (size_t)B_ * LP * D_;        // packed [280*32*64*8] 9.18 MB
  u16* Wpk = Upk + (size_t)YT32 * 32 * 512;    //                     9.18 MB
  float* part = (float*)(Wpk + (size_t)YT32 * 32 * 512);  // [B][70][NS][256] 2.29 MB

  hipMemsetAsync(out + (size_t)B_ * Y_, 0, sizeof(float), stream);
  cvt_x_kernel<<<dim3((B_ * LP * 64) / 256), 256, 0, stream>>>(x, xb);
  cvt_wpk_kernel<<<dim3((2 * YT32 * 32 * 64) / 256), 256, 0, stream>>>(U, Wf, Upk, Wpk);
  fused_kernel<<<dim3(YP / BLK, B_, NS), 256, 0, stream>>>(xb, Upk, Wpk, part);
  combine_kernel<<<dim3((B_ * Y_ + 255) / 256), 256, 0, stream>>>(part, bias, target, out);
}